// Round 7
// baseline (198.895 us; speedup 1.0000x reference)
//
#include <hip/hip_runtime.h>

// Fused transformer block in bf16 MFMA (gfx950 16x16x32), fp32 residuals.
// One wave processes M-tiles of 16 seq-rows (2 seqs) end-to-end; A/B pair of
// tiles interleaved for ILP. Wave-private LDS contexts (in-order LDS pipe per
// wave) -> NO barriers. Layout/masks/dataflow = round 5 (verified passing).
//
// Round-7 change vs round-5 (ONE delta):
//  - FF weights (w1,w2: 64 regs) streamed from d_ws (packed by pack_w) in
//    staggered 16-reg batches -> total unified regs ~150 -> 3 waves/SIMD.
//  - HOST fallback: if ws_size < 16KB, launch the round-5 kernel verbatim
//    (resident FF weights). Isolates the d_ws hypothesis from round 6's NaN.

typedef __attribute__((ext_vector_type(8))) short        bf16x8;
typedef __attribute__((ext_vector_type(4))) float        f32x4;
typedef __attribute__((ext_vector_type(4))) int          i32x4;
typedef __attribute__((ext_vector_type(2))) unsigned int u32x2;

#define THREADS 256
#define TPB 64   // tiles per block
#define TPW 16   // tiles per wave

// per-context LDS offsets (bytes), PHASE-ALIASED — round-5 layout, verified:
#define LDS_X     0      // [16][40] bf16 (1280B)   P1
#define LDS_QK    1280   // [16][72] bf16 (2304B)   P1-P2
#define LDS_VT    3584   // [32][24] bf16 (1536B)   P1-P3
#define LDS_P2    5120   // 2x[16][40] bf16 (2560B) P2-P3
#define LDS_ATTN  0      // [16][40] (1280B)        P3-P4  (over X)
#define LDS_X2    1280   // [16][40] (1280B)        P4-P5  (over QK)
#define LDS_HID   2560   // [16][152] (4864B)       P5-P6  (stride 304)
#define LDS_OUT   0      // [16][36] f32 (2304B)    P6     (over ATTN/X2)
#define LDS_CTX   7680

__device__ __forceinline__ unsigned pk_bf16(float a, float b) {
    unsigned r;
    asm("v_cvt_pk_bf16_f32 %0, %1, %2" : "=v"(r) : "v"(a), "v"(b));
    return r;
}

union frag_u { i32x4 i; bf16x8 b; };

// A/B-frag gather of a weight matrix column: elem j = p[(8g+j)*ldk] * s
__device__ __forceinline__ bf16x8 gather_w(const float* p, int ldk, int g, float s) {
    frag_u r;
    #pragma unroll
    for (int jj = 0; jj < 4; ++jj) {
        float a = p[(8 * g + 2 * jj) * ldk] * s;
        float b = p[(8 * g + 2 * jj + 1) * ldk] * s;
        r.i[jj] = (int)pk_bf16(a, b);
    }
    return r.b;
}

// ---- setup: pack FF weight fragments into d_ws (16 KB), one wave ----
__global__ void pack_w(const float* __restrict__ Wff1,
                       const float* __restrict__ Wff2,
                       i32x4* __restrict__ ws)
{
    const int lane = threadIdx.x & 63;
    const int g = lane >> 4, c = lane & 15;
    #pragma unroll
    for (int n = 0; n < 8; ++n) {
        frag_u f; f.b = gather_w(Wff1 + 16 * n + c, 128, g, 1.f);
        ws[n * 64 + lane] = f.i;
    }
    #pragma unroll
    for (int n = 0; n < 2; ++n)
        #pragma unroll
        for (int ks = 0; ks < 4; ++ks) {
            frag_u f; f.b = gather_w(Wff2 + ks * 1024 + 16 * n + c, 32, g, 1.f);
            ws[(8 + n * 4 + ks) * 64 + lane] = f.i;
        }
}

// ---------------- phase helpers (round-5 bodies, offsets compile-time) ------

__device__ __forceinline__ void ph_stage(char* Wc, int lane, const f32x4& xa, const f32x4& xb) {
    i32x4 xi = { (int)pk_bf16(xa[0], xa[1]), (int)pk_bf16(xa[2], xa[3]),
                 (int)pk_bf16(xb[0], xb[1]), (int)pk_bf16(xb[2], xb[3]) };
    *(i32x4*)(void*)(Wc + LDS_X + (lane >> 2) * 80 + (lane & 3) * 16) = xi;
}

__device__ __forceinline__ void ph_qkv(char* Wc, int c, int g,
                                       const bf16x8 (&wqk)[4], const bf16x8 (&wv)[2]) {
    const f32x4 z4 = {0.f, 0.f, 0.f, 0.f};
    frag_u xf; xf.i = *(i32x4*)(void*)(Wc + LDS_X + c * 80 + g * 16);
    #pragma unroll
    for (int n = 0; n < 4; ++n) {
        f32x4 qc = __builtin_amdgcn_mfma_f32_16x16x32_bf16(wqk[n], xf.b, z4, 0, 0, 0);
        u32x2 w64 = { pk_bf16(qc[0], qc[1]), pk_bf16(qc[2], qc[3]) };
        *(u32x2*)(void*)(Wc + LDS_QK + c * 144 + (16 * n + 4 * g) * 2) = w64;
    }
    #pragma unroll
    for (int n = 0; n < 2; ++n) {
        f32x4 vc = __builtin_amdgcn_mfma_f32_16x16x32_bf16(xf.b, wv[n], z4, 0, 0, 0);
        u32x2 w64 = { pk_bf16(vc[0], vc[1]), pk_bf16(vc[2], vc[3]) };
        *(u32x2*)(void*)(Wc + LDS_VT + (16 * n + c) * 48 + 8 * g) = w64;
    }
}

__device__ __forceinline__ void ph_scores(char* Wc, int c, int g,
                                          const f32x4& mf, const i32x4& mQK) {
    const f32x4 z4 = {0.f, 0.f, 0.f, 0.f};
    #pragma unroll
    for (int h = 0; h < 4; ++h) {
        frag_u kf, qf;
        kf.i = *(i32x4*)(void*)(Wc + LDS_QK + c * 144 + 32 * h);
        qf.i = *(i32x4*)(void*)(Wc + LDS_QK + c * 144 + 32 * h + 16);
        kf.i &= mQK; qf.i &= mQK;
        f32x4 sT = __builtin_amdgcn_mfma_f32_16x16x32_bf16(kf.b, qf.b, z4, 0, 0, 0);
        float e0 = __builtin_amdgcn_exp2f(sT[0]) * mf[0];
        float e1 = __builtin_amdgcn_exp2f(sT[1]) * mf[1];
        float e2 = __builtin_amdgcn_exp2f(sT[2]) * mf[2];
        float e3 = __builtin_amdgcn_exp2f(sT[3]) * mf[3];
        float s = (e0 + e1) + (e2 + e3);
        s += __shfl_xor(s, 16);
        s += __shfl_xor(s, 32);
        float rs = __builtin_amdgcn_rcpf(s);
        u32x2 w64 = { pk_bf16(e0 * rs, e1 * rs), pk_bf16(e2 * rs, e3 * rs) };
        *(u32x2*)(void*)(Wc + LDS_P2 + (h >> 1) * 1280 + c * 80 + ((h & 1) * 16 + 4 * g) * 2) = w64;
    }
}

__device__ __forceinline__ void ph_pv(char* Wc, int c, int g, const i32x4& mPV) {
    const f32x4 z4 = {0.f, 0.f, 0.f, 0.f};
    #pragma unroll
    for (int p = 0; p < 2; ++p) {
        frag_u va, pb;
        va.i = *(i32x4*)(void*)(Wc + LDS_VT + (16 * p + c) * 48 + (g & 1) * 16);
        va.i &= mPV;
        pb.i = *(i32x4*)(void*)(Wc + LDS_P2 + p * 1280 + c * 80 + g * 16);
        f32x4 pv = __builtin_amdgcn_mfma_f32_16x16x32_bf16(va.b, pb.b, z4, 0, 0, 0);
        u32x2 w64 = { pk_bf16(pv[0], pv[1]), pk_bf16(pv[2], pv[3]) };
        *(u32x2*)(void*)(Wc + LDS_ATTN + c * 80 + (16 * p + 4 * g) * 2) = w64;
    }
}

__device__ __forceinline__ void ph_proj(char* Wc, int c, int g, const bf16x8 (&wp)[2],
                                        const f32x4& rx0, const f32x4& rx1, f32x4 (&x2c)[2]) {
    frag_u af; af.i = *(i32x4*)(void*)(Wc + LDS_ATTN + c * 80 + g * 16);
    #pragma unroll
    for (int n = 0; n < 2; ++n) {
        const f32x4 z4 = {0.f, 0.f, 0.f, 0.f};
        f32x4 pc = __builtin_amdgcn_mfma_f32_16x16x32_bf16(wp[n], af.b, z4, 0, 0, 0);
        f32x4 rx = (n == 0) ? rx0 : rx1;
        #pragma unroll
        for (int r = 0; r < 4; ++r) x2c[n][r] = pc[r] + rx[r];
        u32x2 w64 = { pk_bf16(x2c[n][0], x2c[n][1]), pk_bf16(x2c[n][2], x2c[n][3]) };
        *(u32x2*)(void*)(Wc + LDS_X2 + c * 80 + (16 * n + 4 * g) * 2) = w64;
    }
}

__device__ __forceinline__ void ph_ff1h(char* Wc, int c, int g,
                                        const bf16x8 (&w1h)[4], int n0,
                                        const bf16x8& bfX) {
    #pragma unroll
    for (int k = 0; k < 4; ++k) {
        const int n = n0 + k;
        const f32x4 z4 = {0.f, 0.f, 0.f, 0.f};
        f32x4 hc = __builtin_amdgcn_mfma_f32_16x16x32_bf16(w1h[k], bfX, z4, 0, 0, 0);
        #pragma unroll
        for (int r = 0; r < 4; ++r) hc[r] = fmaxf(hc[r], 0.f);
        u32x2 w64 = { pk_bf16(hc[0], hc[1]), pk_bf16(hc[2], hc[3]) };
        *(u32x2*)(void*)(Wc + LDS_HID + c * 304 + (16 * n + 4 * g) * 2) = w64;
    }
}

__device__ __forceinline__ void ph_ff2(char* Wc, int c, int g,
                                       const bf16x8 (&w2a)[4], const bf16x8 (&w2b)[4],
                                       const f32x4 (&x2c)[2]) {
    frag_u hf0, hf1, hf2, hf3;
    hf0.i = *(i32x4*)(void*)(Wc + LDS_HID + c * 304 + 0 * 64 + g * 16);
    hf1.i = *(i32x4*)(void*)(Wc + LDS_HID + c * 304 + 1 * 64 + g * 16);
    hf2.i = *(i32x4*)(void*)(Wc + LDS_HID + c * 304 + 2 * 64 + g * 16);
    hf3.i = *(i32x4*)(void*)(Wc + LDS_HID + c * 304 + 3 * 64 + g * 16);
    {
        f32x4 oc = x2c[0];
        oc = __builtin_amdgcn_mfma_f32_16x16x32_bf16(w2a[0], hf0.b, oc, 0, 0, 0);
        oc = __builtin_amdgcn_mfma_f32_16x16x32_bf16(w2a[1], hf1.b, oc, 0, 0, 0);
        oc = __builtin_amdgcn_mfma_f32_16x16x32_bf16(w2a[2], hf2.b, oc, 0, 0, 0);
        oc = __builtin_amdgcn_mfma_f32_16x16x32_bf16(w2a[3], hf3.b, oc, 0, 0, 0);
        *(f32x4*)(void*)(Wc + LDS_OUT + c * 144 + 4 * g * 4) = oc;
    }
    {
        f32x4 oc = x2c[1];
        oc = __builtin_amdgcn_mfma_f32_16x16x32_bf16(w2b[0], hf0.b, oc, 0, 0, 0);
        oc = __builtin_amdgcn_mfma_f32_16x16x32_bf16(w2b[1], hf1.b, oc, 0, 0, 0);
        oc = __builtin_amdgcn_mfma_f32_16x16x32_bf16(w2b[2], hf2.b, oc, 0, 0, 0);
        oc = __builtin_amdgcn_mfma_f32_16x16x32_bf16(w2b[3], hf3.b, oc, 0, 0, 0);
        *(f32x4*)(void*)(Wc + LDS_OUT + c * 144 + (16 + 4 * g) * 4) = oc;
    }
}

__device__ __forceinline__ void ph_store(char* Wc, int lane, float* outg) {
    f32x4 r0 = *(f32x4*)(void*)(Wc + LDS_OUT + (lane >> 2) * 144 + (lane & 3) * 32);
    f32x4 r1 = *(f32x4*)(void*)(Wc + LDS_OUT + (lane >> 2) * 144 + (lane & 3) * 32 + 16);
    *(f32x4*)(outg + lane * 8)     = r0;
    *(f32x4*)(outg + lane * 8 + 4) = r1;
}

// ------------------ shared prologue computation (both kernels) --------------

struct Prolog {
    bf16x8 wqk[4], wv[2], wp[2];
    f32x4 mf;
    i32x4 mQK, mPV;
};

__device__ __forceinline__ void make_prolog(Prolog& P, const float* Wattn,
                                            const float* Wproj, int lane, int g, int c) {
    const float wscale = 0.5050098f;   // sqrt(32^-0.5 * log2(e))
    #pragma unroll
    for (int n = 0; n < 4; ++n)
        P.wqk[n] = gather_w(Wattn + n * 768 + c, 24, g, wscale);
    #pragma unroll
    for (int n = 0; n < 2; ++n) {
        int vch = 16 * n + c;
        P.wv[n] = gather_w(Wattn + (vch >> 3) * 768 + 16 + (vch & 7), 24, g, 1.f);
    }
    #pragma unroll
    for (int n = 0; n < 2; ++n)
        P.wp[n] = gather_w(Wproj + 16 * n + c, 32, g, 1.f);
    #pragma unroll
    for (int r = 0; r < 4; ++r) {
        int key = 4 * g + r;
        P.mf[r] = ((key >> 3) == (c >> 3) && (key & 7) <= (c & 7)) ? 1.f : 0.f;
    }
    const int b0 = (lane < 16) ? -1 : 0;
    const int b1 = (((lane >> 3) & 1) == ((lane >> 5) & 1)) ? -1 : 0;
    P.mQK = i32x4{b0, b0, b0, b0};
    P.mPV = i32x4{b1, b1, b1, b1};
}

// ----------------------- main kernel (FF weights streamed) ------------------

__global__ __launch_bounds__(THREADS)
void block_mfma_ws(const float* __restrict__ X,
                   const float* __restrict__ Wattn,
                   const float* __restrict__ Wproj,
                   const i32x4* __restrict__ WT,
                   float* __restrict__ Out,
                   int ntiles)
{
    __shared__ __align__(16) char smem[4 * 2 * LDS_CTX];

    const int lane = threadIdx.x & 63;
    const int wid  = threadIdx.x >> 6;
    const int g    = lane >> 4;
    const int c    = lane & 15;
    char* WA = smem + wid * (2 * LDS_CTX);
    char* WB = WA + LDS_CTX;

    Prolog P;
    make_prolog(P, Wattn, Wproj, lane, g, c);

    const int tile0 = blockIdx.x * TPB + wid * TPW;
    if (tile0 >= ntiles) return;

    int p0 = tile0, p1 = (tile0 + 1 < ntiles) ? tile0 + 1 : ntiles - 1;
    f32x4 xaA = *(const f32x4*)(X + (size_t)p0 * 512 + lane * 8);
    f32x4 xbA = *(const f32x4*)(X + (size_t)p0 * 512 + lane * 8 + 4);
    f32x4 xaB = *(const f32x4*)(X + (size_t)p1 * 512 + lane * 8);
    f32x4 xbB = *(const f32x4*)(X + (size_t)p1 * 512 + lane * 8 + 4);

    #pragma unroll 1
    for (int it = 0; it < TPW; it += 2) {
        const int iA = tile0 + it;
        const int iB = tile0 + it + 1;
        const int ttA = (iA < ntiles) ? iA : ntiles - 1;
        const int ttB = (iB < ntiles) ? iB : ntiles - 1;
        const float* xgA = X + (size_t)ttA * 512;
        const float* xgB = X + (size_t)ttB * 512;

        f32x4 rxA0 = *(const f32x4*)(xgA + c * 32 + 4 * g);
        f32x4 rxA1 = *(const f32x4*)(xgA + c * 32 + 16 + 4 * g);
        f32x4 rxB0 = *(const f32x4*)(xgB + c * 32 + 4 * g);
        f32x4 rxB1 = *(const f32x4*)(xgB + c * 32 + 16 + 4 * g);

        ph_stage(WA, lane, xaA, xbA);
        ph_stage(WB, lane, xaB, xbB);

        {
            int nA = (it + 2 < TPW && iA + 2 < ntiles) ? iA + 2 : ttA;
            int nB = (it + 3 < TPW && iB + 2 < ntiles) ? iB + 2 : ttB;
            xaA = *(const f32x4*)(X + (size_t)nA * 512 + lane * 8);
            xbA = *(const f32x4*)(X + (size_t)nA * 512 + lane * 8 + 4);
            xaB = *(const f32x4*)(X + (size_t)nB * 512 + lane * 8);
            xbB = *(const f32x4*)(X + (size_t)nB * 512 + lane * 8 + 4);
        }

        ph_qkv(WA, c, g, P.wqk, P.wv);
        ph_qkv(WB, c, g, P.wqk, P.wv);

        // w1 low batch (global loads; latency covered by scores/pv)
        bf16x8 w1lo[4];
        #pragma unroll
        for (int k = 0; k < 4; ++k) { frag_u t; t.i = WT[k * 64 + lane]; w1lo[k] = t.b; }

        ph_scores(WA, c, g, P.mf, P.mQK);
        ph_scores(WB, c, g, P.mf, P.mQK);

        bf16x8 w1hi[4];
        #pragma unroll
        for (int k = 0; k < 4; ++k) { frag_u t; t.i = WT[(4 + k) * 64 + lane]; w1hi[k] = t.b; }

        ph_pv(WA, c, g, P.mPV);
        ph_pv(WB, c, g, P.mPV);

        f32x4 x2A[2], x2B[2];
        ph_proj(WA, c, g, P.wp, rxA0, rxA1, x2A);
        ph_proj(WB, c, g, P.wp, rxB0, rxB1, x2B);

        frag_u bfA; bfA.i = *(i32x4*)(void*)(WA + LDS_X2 + c * 80 + g * 16);
        frag_u bfB; bfB.i = *(i32x4*)(void*)(WB + LDS_X2 + c * 80 + g * 16);

        bf16x8 w2lo[4];
        #pragma unroll
        for (int k = 0; k < 4; ++k) { frag_u t; t.i = WT[(8 + k) * 64 + lane]; w2lo[k] = t.b; }

        ph_ff1h(WA, c, g, w1lo, 0, bfA.b);
        ph_ff1h(WA, c, g, w1hi, 4, bfA.b);

        bf16x8 w2hi[4];
        #pragma unroll
        for (int k = 0; k < 4; ++k) { frag_u t; t.i = WT[(12 + k) * 64 + lane]; w2hi[k] = t.b; }

        ph_ff1h(WB, c, g, w1lo, 0, bfB.b);
        ph_ff1h(WB, c, g, w1hi, 4, bfB.b);

        ph_ff2(WA, c, g, w2lo, w2hi, x2A);
        if (iA < ntiles) ph_store(WA, lane, Out + (size_t)iA * 512);

        ph_ff2(WB, c, g, w2lo, w2hi, x2B);
        if (iB < ntiles) ph_store(WB, lane, Out + (size_t)iB * 512);
    }
}

// ----------------- fallback kernel (round-5: FF weights resident) -----------

__global__ __launch_bounds__(THREADS)
void block_mfma_reg(const float* __restrict__ X,
                    const float* __restrict__ Wattn,
                    const float* __restrict__ Wproj,
                    const float* __restrict__ Wff1,
                    const float* __restrict__ Wff2,
                    float* __restrict__ Out,
                    int ntiles)
{
    __shared__ __align__(16) char smem[4 * 2 * LDS_CTX];

    const int lane = threadIdx.x & 63;
    const int wid  = threadIdx.x >> 6;
    const int g    = lane >> 4;
    const int c    = lane & 15;
    char* WA = smem + wid * (2 * LDS_CTX);
    char* WB = WA + LDS_CTX;

    Prolog P;
    make_prolog(P, Wattn, Wproj, lane, g, c);

    bf16x8 w1lo[4], w1hi[4], w2lo[4], w2hi[4];
    #pragma unroll
    for (int k = 0; k < 4; ++k) {
        w1lo[k] = gather_w(Wff1 + 16 * k + c, 128, g, 1.f);
        w1hi[k] = gather_w(Wff1 + 16 * (4 + k) + c, 128, g, 1.f);
        w2lo[k] = gather_w(Wff2 + k * 1024 + c, 32, g, 1.f);
        w2hi[k] = gather_w(Wff2 + k * 1024 + 16 + c, 32, g, 1.f);
    }

    const int tile0 = blockIdx.x * TPB + wid * TPW;
    if (tile0 >= ntiles) return;

    int p0 = tile0, p1 = (tile0 + 1 < ntiles) ? tile0 + 1 : ntiles - 1;
    f32x4 xaA = *(const f32x4*)(X + (size_t)p0 * 512 + lane * 8);
    f32x4 xbA = *(const f32x4*)(X + (size_t)p0 * 512 + lane * 8 + 4);
    f32x4 xaB = *(const f32x4*)(X + (size_t)p1 * 512 + lane * 8);
    f32x4 xbB = *(const f32x4*)(X + (size_t)p1 * 512 + lane * 8 + 4);

    #pragma unroll 1
    for (int it = 0; it < TPW; it += 2) {
        const int iA = tile0 + it;
        const int iB = tile0 + it + 1;
        const int ttA = (iA < ntiles) ? iA : ntiles - 1;
        const int ttB = (iB < ntiles) ? iB : ntiles - 1;
        const float* xgA = X + (size_t)ttA * 512;
        const float* xgB = X + (size_t)ttB * 512;

        f32x4 rxA0 = *(const f32x4*)(xgA + c * 32 + 4 * g);
        f32x4 rxA1 = *(const f32x4*)(xgA + c * 32 + 16 + 4 * g);
        f32x4 rxB0 = *(const f32x4*)(xgB + c * 32 + 4 * g);
        f32x4 rxB1 = *(const f32x4*)(xgB + c * 32 + 16 + 4 * g);

        ph_stage(WA, lane, xaA, xbA);
        ph_stage(WB, lane, xaB, xbB);

        {
            int nA = (it + 2 < TPW && iA + 2 < ntiles) ? iA + 2 : ttA;
            int nB = (it + 3 < TPW && iB + 2 < ntiles) ? iB + 2 : ttB;
            xaA = *(const f32x4*)(X + (size_t)nA * 512 + lane * 8);
            xbA = *(const f32x4*)(X + (size_t)nA * 512 + lane * 8 + 4);
            xaB = *(const f32x4*)(X + (size_t)nB * 512 + lane * 8);
            xbB = *(const f32x4*)(X + (size_t)nB * 512 + lane * 8 + 4);
        }

        ph_qkv(WA, c, g, P.wqk, P.wv);
        ph_qkv(WB, c, g, P.wqk, P.wv);

        ph_scores(WA, c, g, P.mf, P.mQK);
        ph_scores(WB, c, g, P.mf, P.mQK);

        ph_pv(WA, c, g, P.mPV);
        ph_pv(WB, c, g, P.mPV);

        f32x4 x2A[2], x2B[2];
        ph_proj(WA, c, g, P.wp, rxA0, rxA1, x2A);
        ph_proj(WB, c, g, P.wp, rxB0, rxB1, x2B);

        frag_u bfA; bfA.i = *(i32x4*)(void*)(WA + LDS_X2 + c * 80 + g * 16);
        frag_u bfB; bfB.i = *(i32x4*)(void*)(WB + LDS_X2 + c * 80 + g * 16);

        ph_ff1h(WA, c, g, w1lo, 0, bfA.b);
        ph_ff1h(WA, c, g, w1hi, 4, bfA.b);
        ph_ff1h(WB, c, g, w1lo, 0, bfB.b);
        ph_ff1h(WB, c, g, w1hi, 4, bfB.b);

        ph_ff2(WA, c, g, w2lo, w2hi, x2A);
        if (iA < ntiles) ph_store(WA, lane, Out + (size_t)iA * 512);

        ph_ff2(WB, c, g, w2lo, w2hi, x2B);
        if (iB < ntiles) ph_store(WB, lane, Out + (size_t)iB * 512);
    }
}

extern "C" void kernel_launch(void* const* d_in, const int* in_sizes, int n_in,
                              void* d_out, int out_size, void* d_ws, size_t ws_size,
                              hipStream_t stream) {
    (void)n_in; (void)out_size;
    const float* X     = (const float*)d_in[0];
    const float* Wattn = (const float*)d_in[1];
    const float* Wproj = (const float*)d_in[2];
    const float* Wff1  = (const float*)d_in[3];
    const float* Wff2  = (const float*)d_in[4];
    float* Out = (float*)d_out;

    const int nseq   = in_sizes[0] / 256;   // (b, 8, 32)
    const int ntiles = nseq / 2;            // 16 rows per tile
    const int blocks = (ntiles + TPB - 1) / TPB;

    if (ws_size >= 16384 && d_ws != nullptr) {
        i32x4* WT = (i32x4*)d_ws;
        pack_w<<<dim3(1), dim3(64), 0, stream>>>(Wff1, Wff2, WT);
        block_mfma_ws<<<dim3(blocks), dim3(THREADS), 0, stream>>>(
            X, Wattn, Wproj, WT, Out, ntiles);
    } else {
        block_mfma_reg<<<dim3(blocks), dim3(THREADS), 0, stream>>>(
            X, Wattn, Wproj, Wff1, Wff2, Out, ntiles);
    }
}